// Round 1
// baseline (5048.772 us; speedup 1.0000x reference)
//
#include <hip/hip_runtime.h>

#define BB    8
#define CIN   512
#define COUT  512
#define SDIM  512
#define HH    32
#define WW    32

// ---------------------------------------------------------------------------
// k_style: m[b,c] = 1 + style[b,:] @ fc_w[c,:] + fc_b[c]
// ---------------------------------------------------------------------------
__global__ void k_style(const float* __restrict__ style, const float* __restrict__ fc_w,
                        const float* __restrict__ fc_b, float* __restrict__ m) {
    __shared__ float sst[SDIM];
    const int b = blockIdx.x;
    for (int k = threadIdx.x; k < SDIM; k += 256) sst[k] = style[b * SDIM + k];
    __syncthreads();
    for (int c = threadIdx.x; c < CIN; c += 256) {
        float acc = fc_b[c];
        const float* wr = fc_w + c * SDIM;
        for (int k = 0; k < SDIM; k += 4) {
            float4 w4 = *(const float4*)(wr + k);
            acc += w4.x * sst[k] + w4.y * sst[k + 1] + w4.z * sst[k + 2] + w4.w * sst[k + 3];
        }
        m[b * CIN + c] = acc + 1.0f;
    }
}

// ---------------------------------------------------------------------------
// k_wprep: per (o,c): q[o,c] = sum_k w^2 ; F[p][o][c][4] = phase-combined 2x2
// weights from the 3x3 kernel under 2x-nearest-upsample + SAME conv.
// Tap index t = i*2+j -> source (r+ry0+i, q+cx0+j).
// ---------------------------------------------------------------------------
__global__ void k_wprep(const float* __restrict__ conv_w, float* __restrict__ q,
                        float* __restrict__ F) {
    const int idx = blockIdx.x * 256 + threadIdx.x;  // o*512 + c
    if (idx >= COUT * CIN) return;
    const int o = idx >> 9, c = idx & 511;
    float w[3][3];
    const float* wp = conv_w + idx * 9;
    float qs = 0.f;
    for (int i = 0; i < 3; i++)
        for (int j = 0; j < 3; j++) {
            float v = wp[i * 3 + j];
            w[i][j] = v;
            qs += v * v;
        }
    q[idx] = qs;
    for (int py = 0; py < 2; py++) {
        float rs[2][3];
        for (int kx = 0; kx < 3; kx++) {
            rs[0][kx] = (py == 0) ? w[0][kx] : w[0][kx] + w[1][kx];
            rs[1][kx] = (py == 0) ? w[1][kx] + w[2][kx] : w[2][kx];
        }
        for (int px = 0; px < 2; px++) {
            const int p = py * 2 + px;
            float4 f;
            if (px == 0) {
                f.x = rs[0][0];
                f.y = rs[0][1] + rs[0][2];
                f.z = rs[1][0];
                f.w = rs[1][1] + rs[1][2];
            } else {
                f.x = rs[0][0] + rs[0][1];
                f.y = rs[0][2];
                f.z = rs[1][0] + rs[1][1];
                f.w = rs[1][2];
            }
            ((float4*)F)[(p * COUT + o) * CIN + c] = f;
        }
    }
}

// ---------------------------------------------------------------------------
// k_demod: d[b,o] = rsqrt( sum_c m[b,c]^2 * q[o,c] + 1e-8 )
// ---------------------------------------------------------------------------
__global__ void k_demod(const float* __restrict__ m, const float* __restrict__ q,
                        float* __restrict__ d) {
    const int idx = blockIdx.x * 256 + threadIdx.x;  // b*512 + o
    const int b = idx >> 9, o = idx & 511;
    const float* mb = m + b * CIN;
    const float* qo = q + o * CIN;
    float acc = 0.f;
    for (int c = 0; c < CIN; c++) {
        float mv = mb[c];
        acc += mv * mv * qo[c];
    }
    d[idx] = rsqrtf(acc + 1e-8f);
}

// ---------------------------------------------------------------------------
// k_conv: main phase-decomposed conv.
// block = (o_chunk of 8, phase p, batch b); 256 threads; each thread owns
// 1 source row x 4 source cols x 8 output channels = 32 accumulators.
// Input channel scaled by m[b,c] at LDS staging; d[b,o] applied at epilogue.
// ---------------------------------------------------------------------------
#define NO 8
#define NC 4
#define TROW 33
#define TILE_ELEMS (TROW * TROW)  // 1089

__global__ __launch_bounds__(256, 4) void k_conv(
    const float* __restrict__ x, const float* __restrict__ noise,
    const float* __restrict__ bias, const float* __restrict__ m,
    const float* __restrict__ d, const float* __restrict__ F,
    float* __restrict__ out) {
    __shared__ float tile[NC][TILE_ELEMS];
    __shared__ float4 wlds[NC][NO];

    const int t = threadIdx.x;
    const int o0 = blockIdx.x * NO;
    const int p = blockIdx.y;
    const int b = blockIdx.z;
    const int py = p >> 1, px = p & 1;
    const int ry0 = py ? 0 : -1;
    const int cx0 = px ? 0 : -1;
    const int row = t >> 3;       // 0..31 (source row / per-phase output row)
    const int qc = (t & 7) * 4;   // source col base, 0..28

    float acc[NO][4];
    for (int ol = 0; ol < NO; ol++)
        for (int j = 0; j < 4; j++) acc[ol][j] = 0.f;

    const float* xb = x + b * CIN * HH * WW;
    const float* mb = m + b * CIN;
    const float4* F4 = (const float4*)F + (size_t)(p * COUT + o0) * CIN;

    for (int c0 = 0; c0 < CIN; c0 += NC) {
        __syncthreads();
        // stage input tile (33x33 with zero pad), scaled by m[b,c]
        for (int idx = t; idx < NC * TILE_ELEMS; idx += 256) {
            const int cl = idx / TILE_ELEMS;
            const int rem = idx - cl * TILE_ELEMS;
            const int tr = rem / TROW;
            const int tc = rem - tr * TROW;
            const int gr = tr + ry0, gc = tc + cx0;
            float v = 0.f;
            if ((unsigned)gr < 32u && (unsigned)gc < 32u)
                v = xb[(c0 + cl) * (HH * WW) + gr * WW + gc] * mb[c0 + cl];
            tile[cl][rem] = v;
        }
        // stage phase weights for this (p, o-chunk, c-chunk)
        if (t < NC * NO) {
            const int cl = t >> 3, ol = t & 7;
            wlds[cl][ol] = F4[ol * CIN + (c0 + cl)];
        }
        __syncthreads();

        for (int cl = 0; cl < NC; cl++) {
            float a0[5], a1[5];
            const float* tr0 = &tile[cl][row * TROW + qc];
            const float* tr1 = tr0 + TROW;
            for (int j = 0; j < 5; j++) {
                a0[j] = tr0[j];
                a1[j] = tr1[j];
            }
            for (int ol = 0; ol < NO; ol++) {
                const float4 w = wlds[cl][ol];
                for (int j = 0; j < 4; j++)
                    acc[ol][j] += w.x * a0[j] + w.y * a0[j + 1] + w.z * a1[j] + w.w * a1[j + 1];
            }
        }
    }

    // epilogue: demod scale + bias + noise + leaky relu
    const int Y = 2 * row + py;
    const float* nz = noise + b * 4096 + Y * 64;
    for (int ol = 0; ol < NO; ol++) {
        const int o = o0 + ol;
        const float dv = d[b * COUT + o];
        const float bv = bias[o];
        float* op = out + ((size_t)(b * COUT + o) * 64 + Y) * 64;
        for (int j = 0; j < 4; j++) {
            const int X = 2 * (qc + j) + px;
            float v = acc[ol][j] * dv + bv + nz[X];
            op[X] = v > 0.f ? v : 0.2f * v;
        }
    }
}

// ---------------------------------------------------------------------------
extern "C" void kernel_launch(void* const* d_in, const int* in_sizes, int n_in,
                              void* d_out, int out_size, void* d_ws, size_t ws_size,
                              hipStream_t stream) {
    const float* x      = (const float*)d_in[0];
    const float* style  = (const float*)d_in[1];
    const float* noise  = (const float*)d_in[2];
    const float* conv_w = (const float*)d_in[3];
    const float* fc_w   = (const float*)d_in[4];
    const float* fc_b   = (const float*)d_in[5];
    const float* bias   = (const float*)d_in[6];
    float* out = (float*)d_out;

    float* ws = (float*)d_ws;
    float* m = ws;                 // 8*512
    float* dmod = ws + 4096;       // 8*512
    float* q = ws + 8192;          // 512*512
    float* F = ws + 270336;        // 4*512*512*4  (16B-aligned offset)

    k_style<<<BB, 256, 0, stream>>>(style, fc_w, fc_b, m);
    k_wprep<<<(COUT * CIN + 255) / 256, 256, 0, stream>>>(conv_w, q, F);
    k_demod<<<(BB * COUT + 255) / 256, 256, 0, stream>>>(m, q, dmod);
    k_conv<<<dim3(COUT / NO, 4, BB), 256, 0, stream>>>(x, noise, bias, m, dmod, F, out);
}

// Round 3
// 320.332 us; speedup vs baseline: 15.7611x; 15.7611x over previous
//
#include <hip/hip_runtime.h>

typedef short v8s __attribute__((ext_vector_type(8)));
typedef float f32x4 __attribute__((ext_vector_type(4)));
typedef unsigned short ushort_t;

#define BB    8
#define CIN   512
#define COUT  512
#define SDIM  512

static __device__ __forceinline__ ushort_t f2bf(float f) {
    union { float f; unsigned u; } un; un.f = f;
    unsigned r = un.u + 0x7FFF + ((un.u >> 16) & 1);  // round-to-nearest-even
    return (ushort_t)(r >> 16);
}

// ---------------------------------------------------------------------------
// m[b,c] = 1 + style[b,:] @ fc_w[c,:] + fc_b[c]
// ---------------------------------------------------------------------------
__global__ void k_style(const float* __restrict__ style, const float* __restrict__ fc_w,
                        const float* __restrict__ fc_b, float* __restrict__ m) {
    __shared__ float sst[SDIM];
    const int b = blockIdx.x;
    for (int k = threadIdx.x; k < SDIM; k += 256) sst[k] = style[b * SDIM + k];
    __syncthreads();
    for (int c = threadIdx.x; c < CIN; c += 256) {
        float acc = fc_b[c];
        const float* wr = fc_w + c * SDIM;
        for (int k = 0; k < SDIM; k += 4) {
            float4 w4 = *(const float4*)(wr + k);
            acc += w4.x * sst[k] + w4.y * sst[k + 1] + w4.z * sst[k + 2] + w4.w * sst[k + 3];
        }
        m[b * CIN + c] = acc + 1.0f;
    }
}

// ---------------------------------------------------------------------------
// q[o,c] = sum_k w^2 ; Wb bf16 phase-combined weights:
// Wb[p][ch=c>>5][t][kg=(c>>3)&3][o][c&7]
// ---------------------------------------------------------------------------
__global__ void k_wprep(const float* __restrict__ conv_w, float* __restrict__ q,
                        ushort_t* __restrict__ Wb) {
    const int idx = blockIdx.x * 256 + threadIdx.x;  // o*512 + c
    if (idx >= COUT * CIN) return;
    const int o = idx >> 9, c = idx & 511;
    float w[3][3];
    const float* wp = conv_w + idx * 9;
    float qs = 0.f;
    for (int i = 0; i < 3; i++)
        for (int j = 0; j < 3; j++) {
            float v = wp[i * 3 + j];
            w[i][j] = v;
            qs += v * v;
        }
    q[idx] = qs;
    const int ch = c >> 5, kg = (c >> 3) & 3, c8 = c & 7;
    for (int py = 0; py < 2; py++) {
        float rs[2][3];
        for (int kx = 0; kx < 3; kx++) {
            rs[0][kx] = (py == 0) ? w[0][kx] : w[0][kx] + w[1][kx];
            rs[1][kx] = (py == 0) ? w[1][kx] + w[2][kx] : w[2][kx];
        }
        for (int px = 0; px < 2; px++) {
            const int p = py * 2 + px;
            float vals[4];
            if (px == 0) {
                vals[0] = rs[0][0];
                vals[1] = rs[0][1] + rs[0][2];
                vals[2] = rs[1][0];
                vals[3] = rs[1][1] + rs[1][2];
            } else {
                vals[0] = rs[0][0] + rs[0][1];
                vals[1] = rs[0][2];
                vals[2] = rs[1][0] + rs[1][1];
                vals[3] = rs[1][2];
            }
            for (int t = 0; t < 4; t++)
                Wb[(size_t)p * (16 * 4 * 4 * 512 * 8) + (size_t)ch * (4 * 4 * 512 * 8)
                   + ((size_t)(t * 4 + kg) * 512 + o) * 8 + c8] = f2bf(vals[t]);
        }
    }
}

// ---------------------------------------------------------------------------
// d[b,o] = rsqrt( sum_c m[b,c]^2 * q[o,c] + 1e-8 )
// ---------------------------------------------------------------------------
__global__ void k_demod(const float* __restrict__ m, const float* __restrict__ q,
                        float* __restrict__ d) {
    const int idx = blockIdx.x * 256 + threadIdx.x;  // b*512 + o
    const int b = idx >> 9, o = idx & 511;
    const float* mb = m + b * CIN;
    const float* qo = q + o * CIN;
    float acc = 0.f;
    for (int c = 0; c < CIN; c++) {
        float mv = mb[c];
        acc += mv * mv * qo[c];
    }
    d[idx] = rsqrtf(acc + 1e-8f);
}

// ---------------------------------------------------------------------------
// Xt[b][r][q][c] = bf16( x[b][c][r][q] * m[b][c] )   (c-contiguous transpose)
// ---------------------------------------------------------------------------
__global__ void k_xprep(const float* __restrict__ x, const float* __restrict__ m,
                        ushort_t* __restrict__ Xt) {
    __shared__ __align__(16) ushort_t lt[32 * 528];  // [q][c], c-stride 528
    const int r = blockIdx.x, b = blockIdx.y, t = threadIdx.x;
    for (int s = t; s < 4096; s += 256) {  // (c, q-quad)
        const int c = s >> 3, q4 = (s & 7) * 4;
        float4 v = *(const float4*)(x + (((size_t)(b * CIN + c) * 32 + r) * 32 + q4));
        const float mv = m[b * CIN + c];
        lt[(q4 + 0) * 528 + c] = f2bf(v.x * mv);
        lt[(q4 + 1) * 528 + c] = f2bf(v.y * mv);
        lt[(q4 + 2) * 528 + c] = f2bf(v.z * mv);
        lt[(q4 + 3) * 528 + c] = f2bf(v.w * mv);
    }
    __syncthreads();
    for (int s = t; s < 2048; s += 256) {  // (q, c-group of 8)
        const int qq = s >> 6, c8 = s & 63;
        v8s v = *(v8s*)&lt[qq * 528 + c8 * 8];
        *(v8s*)(Xt + (((size_t)(b * 32 + r) * 32 + qq) * 512 + c8 * 8)) = v;
    }
}

// ---------------------------------------------------------------------------
// k_gemm: per (b,p): O[o, n] = sum_{k=0..127} Wt[o][k] * Xs[n][k] per chunk,
// where k = tap*32 + channel. Tap pairing is via the shared k index — correct
// by construction. Block: 64 o x 64 n (2 source rows), 4 waves of 32x32.
// ---------------------------------------------------------------------------
#define KS 136  // padded k-stride (272 B: 16B-aligned, 2-way banks only)

__global__ __launch_bounds__(256, 3) void k_gemm(
    const ushort_t* __restrict__ Xt, const ushort_t* __restrict__ Wb,
    const float* __restrict__ dmod, const float* __restrict__ bias,
    const float* __restrict__ noise, float* __restrict__ out) {
    __shared__ __align__(16) ushort_t Wt[64 * KS];  // [o-local][k]
    __shared__ __align__(16) ushort_t Xs[64 * KS];  // [n-local][k]

    const int tid = threadIdx.x;
    const int L = tid & 63, wid = tid >> 6;
    const int o0 = blockIdx.x * 64;
    const int r0 = blockIdx.y * 2;
    const int b = blockIdx.z >> 2, p = blockIdx.z & 3;
    const int py = p >> 1, px = p & 1;
    const int ry0 = py ? 0 : -1, cx0 = px ? 0 : -1;
    const int wo = (wid >> 1) * 32, wn = (wid & 1) * 32;
    const int l15 = L & 15, l4 = L >> 4;

    const ushort_t* XtB = Xt + (size_t)b * (32 * 32 * 512);
    const ushort_t* WbP = Wb + (size_t)p * (16 * 4 * 4 * 512 * 8);
    const v8s z8 = {0, 0, 0, 0, 0, 0, 0, 0};

    f32x4 acc[2][2];
#pragma unroll
    for (int i = 0; i < 2; i++)
#pragma unroll
        for (int j = 0; j < 2; j++) acc[i][j] = {0.f, 0.f, 0.f, 0.f};

    for (int c0 = 0; c0 < CIN; c0 += 32) {
        __syncthreads();
        const ushort_t* WbC = WbP + (size_t)(c0 >> 5) * (4 * 4 * 512 * 8);
        // stage both tiles: 1024 slots each = [row 64][t 4][cg 4]
#pragma unroll
        for (int i = 0; i < 4; i++) {
            const int slot = tid + i * 256;
            const int row = slot >> 4, t = (slot >> 2) & 3, cg = slot & 3;
            const int ldso = row * KS + t * 32 + cg * 8;
            // W tile: Wt[row][t*32+cg*8+j] = W[t][o0+row][c0+cg*8+j]
            *(v8s*)&Wt[ldso] =
                *(const v8s*)(WbC + ((size_t)((t * 4 + cg) * 512 + o0 + row)) * 8);
            // X tile: Xs[row][t*32+cg*8+j] = X[r0+(row>>5)+ry0+ty][ (row&31)+cx0+tx ][c0+cg*8+j]
            const int gr = r0 + (row >> 5) + ry0 + (t >> 1);
            const int gq = (row & 31) + cx0 + (t & 1);
            v8s xv = z8;
            if ((unsigned)gr < 32u && (unsigned)gq < 32u)
                xv = *(const v8s*)(XtB + (size_t)((gr * 32 + gq) * 512 + c0 + cg * 8));
            *(v8s*)&Xs[ldso] = xv;
        }
        __syncthreads();
        // 4 k-steps of 32 (one per tap), 2x2 MFMA each
#pragma unroll
        for (int s = 0; s < 4; s++) {
            const int kb = s * 32 + l4 * 8;
            v8s af[2], bf[2];
#pragma unroll
            for (int i = 0; i < 2; i++)
                af[i] = *(const v8s*)&Wt[(wo + i * 16 + l15) * KS + kb];
#pragma unroll
            for (int j = 0; j < 2; j++)
                bf[j] = *(const v8s*)&Xs[(wn + j * 16 + l15) * KS + kb];
#pragma unroll
            for (int i = 0; i < 2; i++)
#pragma unroll
                for (int j = 0; j < 2; j++)
                    acc[i][j] = __builtin_amdgcn_mfma_f32_16x16x32_bf16(
                        af[i], bf[j], acc[i][j], 0, 0, 0);
        }
    }

    // ---- epilogue: demod * acc + bias + noise, leaky relu ----
    const float* db = dmod + b * COUT;
    float nz[2];
    int ooff[2];
#pragma unroll
    for (int j = 0; j < 2; j++) {
        const int n = wn + j * 16 + l15;
        const int Y = 2 * (r0 + (n >> 5)) + py, X = 2 * (n & 31) + px;
        nz[j] = noise[b * 4096 + Y * 64 + X];
        ooff[j] = Y * 64 + X;
    }
    float* outB = out + (size_t)b * COUT * 4096;
#pragma unroll
    for (int i = 0; i < 2; i++) {
        const int ob = o0 + wo + i * 16 + l4 * 4;
        float4 d4 = *(const float4*)(db + ob);
        float4 b4 = *(const float4*)(bias + ob);
        const float dv[4] = {d4.x, d4.y, d4.z, d4.w};
        const float bv[4] = {b4.x, b4.y, b4.z, b4.w};
#pragma unroll
        for (int reg = 0; reg < 4; reg++) {
            float* orow = outB + (size_t)(ob + reg) * 4096;
#pragma unroll
            for (int j = 0; j < 2; j++) {
                float v = acc[i][j][reg] * dv[reg] + bv[reg] + nz[j];
                orow[ooff[j]] = v > 0.f ? v : 0.2f * v;
            }
        }
    }
}

// ---------------------------------------------------------------------------
extern "C" void kernel_launch(void* const* d_in, const int* in_sizes, int n_in,
                              void* d_out, int out_size, void* d_ws, size_t ws_size,
                              hipStream_t stream) {
    const float* x      = (const float*)d_in[0];
    const float* style  = (const float*)d_in[1];
    const float* noise  = (const float*)d_in[2];
    const float* conv_w = (const float*)d_in[3];
    const float* fc_w   = (const float*)d_in[4];
    const float* fc_b   = (const float*)d_in[5];
    const float* bias   = (const float*)d_in[6];
    float* out = (float*)d_out;

    float* ws = (float*)d_ws;
    float* m    = ws;            // 8*512
    float* dmod = ws + 4096;     // 8*512
    float* q    = ws + 8192;     // 512*512
    ushort_t* XtU = (ushort_t*)(ws + 270336);  // 8*32*32*512 bf16
    ushort_t* WbU = XtU + 4194304;             // 4*16*4*4*512*8 bf16

    k_style<<<BB, 256, 0, stream>>>(style, fc_w, fc_b, m);
    k_wprep<<<(COUT * CIN + 255) / 256, 256, 0, stream>>>(conv_w, q, WbU);
    k_xprep<<<dim3(32, BB), 256, 0, stream>>>(x, m, XtU);
    k_demod<<<(BB * COUT + 255) / 256, 256, 0, stream>>>(m, q, dmod);
    k_gemm<<<dim3(8, 16, 32), 256, 0, stream>>>(XtU, WbU, dmod, bias, noise, out);
}

// Round 6
// 310.512 us; speedup vs baseline: 16.2595x; 1.0316x over previous
//
#include <hip/hip_runtime.h>

typedef short v8s __attribute__((ext_vector_type(8)));
typedef float f32x4 __attribute__((ext_vector_type(4)));
typedef unsigned short ushort_t;

#define BB    8
#define CIN   512
#define COUT  512
#define SDIM  512

static __device__ __forceinline__ ushort_t f2bf(float f) {
    union { float f; unsigned u; } un; un.f = f;
    unsigned r = un.u + 0x7FFF + ((un.u >> 16) & 1);  // round-to-nearest-even
    return (ushort_t)(r >> 16);
}

// ---------------------------------------------------------------------------
// m[b,c] = 1 + style[b,:] @ fc_w[c,:] + fc_b[c]
// ---------------------------------------------------------------------------
__global__ void k_style(const float* __restrict__ style, const float* __restrict__ fc_w,
                        const float* __restrict__ fc_b, float* __restrict__ m) {
    __shared__ float sst[SDIM];
    const int b = blockIdx.x;
    for (int k = threadIdx.x; k < SDIM; k += 256) sst[k] = style[b * SDIM + k];
    __syncthreads();
    for (int c = threadIdx.x; c < CIN; c += 256) {
        float acc = fc_b[c];
        const float* wr = fc_w + c * SDIM;
        for (int k = 0; k < SDIM; k += 4) {
            float4 w4 = *(const float4*)(wr + k);
            acc += w4.x * sst[k] + w4.y * sst[k + 1] + w4.z * sst[k + 2] + w4.w * sst[k + 3];
        }
        m[b * CIN + c] = acc + 1.0f;
    }
}

// ---------------------------------------------------------------------------
// q[o,c] = sum_k w^2 ; Wb bf16 phase-combined weights:
// Wb[p][ch=c>>5][t][kg=(c>>3)&3][o][c&7]
// ---------------------------------------------------------------------------
__global__ void k_wprep(const float* __restrict__ conv_w, float* __restrict__ q,
                        ushort_t* __restrict__ Wb) {
    const int idx = blockIdx.x * 256 + threadIdx.x;  // o*512 + c
    if (idx >= COUT * CIN) return;
    const int o = idx >> 9, c = idx & 511;
    float w[3][3];
    const float* wp = conv_w + idx * 9;
    float qs = 0.f;
    for (int i = 0; i < 3; i++)
        for (int j = 0; j < 3; j++) {
            float v = wp[i * 3 + j];
            w[i][j] = v;
            qs += v * v;
        }
    q[idx] = qs;
    const int ch = c >> 5, kg = (c >> 3) & 3, c8 = c & 7;
    for (int py = 0; py < 2; py++) {
        float rs[2][3];
        for (int kx = 0; kx < 3; kx++) {
            rs[0][kx] = (py == 0) ? w[0][kx] : w[0][kx] + w[1][kx];
            rs[1][kx] = (py == 0) ? w[1][kx] + w[2][kx] : w[2][kx];
        }
        for (int px = 0; px < 2; px++) {
            const int p = py * 2 + px;
            float vals[4];
            if (px == 0) {
                vals[0] = rs[0][0];
                vals[1] = rs[0][1] + rs[0][2];
                vals[2] = rs[1][0];
                vals[3] = rs[1][1] + rs[1][2];
            } else {
                vals[0] = rs[0][0] + rs[0][1];
                vals[1] = rs[0][2];
                vals[2] = rs[1][0] + rs[1][1];
                vals[3] = rs[1][2];
            }
            for (int t = 0; t < 4; t++)
                Wb[(size_t)p * (16 * 4 * 4 * 512 * 8) + (size_t)ch * (4 * 4 * 512 * 8)
                   + ((size_t)(t * 4 + kg) * 512 + o) * 8 + c8] = f2bf(vals[t]);
        }
    }
}

// ---------------------------------------------------------------------------
// d[b,o] = rsqrt( sum_c m[b,c]^2 * q[o,c] + 1e-8 ) — one wave per (b,o)
// ---------------------------------------------------------------------------
__global__ void k_demod(const float* __restrict__ m, const float* __restrict__ q,
                        float* __restrict__ d) {
    const int w = (blockIdx.x * 256 + threadIdx.x) >> 6;  // 0..4095
    const int L = threadIdx.x & 63;
    const int b = w >> 9, o = w & 511;
    float4 q1 = *(const float4*)(q + o * 512 + L * 8);
    float4 q2 = *(const float4*)(q + o * 512 + L * 8 + 4);
    float4 m1 = *(const float4*)(m + b * 512 + L * 8);
    float4 m2 = *(const float4*)(m + b * 512 + L * 8 + 4);
    float acc = m1.x * m1.x * q1.x + m1.y * m1.y * q1.y + m1.z * m1.z * q1.z +
                m1.w * m1.w * q1.w + m2.x * m2.x * q2.x + m2.y * m2.y * q2.y +
                m2.z * m2.z * q2.z + m2.w * m2.w * q2.w;
    for (int off = 32; off; off >>= 1) acc += __shfl_down(acc, off, 64);
    if (L == 0) d[w] = rsqrtf(acc + 1e-8f);
}

// ---------------------------------------------------------------------------
// Xt[b][r][q][c] = bf16( x[b][c][r][q] * m[b][c] )   (c-contiguous transpose)
// ---------------------------------------------------------------------------
__global__ void k_xprep(const float* __restrict__ x, const float* __restrict__ m,
                        ushort_t* __restrict__ Xt) {
    __shared__ __align__(16) ushort_t lt[32 * 528];  // [q][c], c-stride 528
    const int r = blockIdx.x, b = blockIdx.y, t = threadIdx.x;
    for (int s = t; s < 4096; s += 256) {  // (c, q-quad)
        const int c = s >> 3, q4 = (s & 7) * 4;
        float4 v = *(const float4*)(x + (((size_t)(b * CIN + c) * 32 + r) * 32 + q4));
        const float mv = m[b * CIN + c];
        lt[(q4 + 0) * 528 + c] = f2bf(v.x * mv);
        lt[(q4 + 1) * 528 + c] = f2bf(v.y * mv);
        lt[(q4 + 2) * 528 + c] = f2bf(v.z * mv);
        lt[(q4 + 3) * 528 + c] = f2bf(v.w * mv);
    }
    __syncthreads();
    for (int s = t; s < 2048; s += 256) {  // (q, c-group of 8)
        const int qq = s >> 6, c8 = s & 63;
        v8s v = *(v8s*)&lt[qq * 528 + c8 * 8];
        *(v8s*)(Xt + (((size_t)(b * 32 + r) * 32 + qq) * 512 + c8 * 8)) = v;
    }
}

// ---------------------------------------------------------------------------
// k_gemm: round-3-verified structure, n-tile widened to 128. Per (b,p):
// O[o,n] = sum_k W[o][k]*X[n][k], k = tap*32 + c_local per 128-wide chunk
// (4 taps x 32 ch), 16 chunks. Block 64o x 128n, 4 waves of 32x64.
// All index formulas verbatim from the round-3 passing kernel.
// ---------------------------------------------------------------------------
#define KS 136  // padded k-stride (272 B: 16B-aligned, 2-way banks only)

__global__ __launch_bounds__(256, 3) void k_gemm(
    const ushort_t* __restrict__ Xt, const ushort_t* __restrict__ Wb,
    const float* __restrict__ dmod, const float* __restrict__ bias,
    const float* __restrict__ noise, float* __restrict__ out) {
    __shared__ __align__(16) ushort_t Wt[64 * KS];   // [o-local][k]
    __shared__ __align__(16) ushort_t Xs[128 * KS];  // [n-local][k]

    const int tid = threadIdx.x;
    const int L = tid & 63, wid = tid >> 6;
    const int o0 = blockIdx.x * 64;
    const int r0 = blockIdx.y * 4;
    const int b = blockIdx.z >> 2, p = blockIdx.z & 3;
    const int py = p >> 1, px = p & 1;
    const int ry0 = py ? 0 : -1, cx0 = px ? 0 : -1;
    const int wo = (wid >> 1) * 32, wn = (wid & 1) * 64;
    const int l15 = L & 15, l4 = L >> 4;

    const ushort_t* XtB = Xt + (size_t)b * (32 * 32 * 512);
    const ushort_t* WbP = Wb + (size_t)p * (16 * 4 * 4 * 512 * 8);
    const v8s z8 = {0, 0, 0, 0, 0, 0, 0, 0};

    f32x4 acc[2][4];
#pragma unroll
    for (int i = 0; i < 2; i++)
#pragma unroll
        for (int j = 0; j < 4; j++) acc[i][j] = {0.f, 0.f, 0.f, 0.f};

    for (int c0 = 0; c0 < CIN; c0 += 32) {
        __syncthreads();
        const ushort_t* WbC = WbP + (size_t)(c0 >> 5) * (4 * 4 * 512 * 8);
        // stage: X slots [row 128][t 4][cg 4] (8 iters); W slots [row 64][t][cg]
        // guarded to the first 1024 — formulas verbatim round 3.
#pragma unroll
        for (int i = 0; i < 8; i++) {
            const int slot = tid + i * 256;
            const int row = slot >> 4, t = (slot >> 2) & 3, cg = slot & 3;
            const int ldso = row * KS + t * 32 + cg * 8;
            if (slot < 1024)
                *(v8s*)&Wt[ldso] =
                    *(const v8s*)(WbC + ((size_t)((t * 4 + cg) * 512 + o0 + row)) * 8);
            const int gr = r0 + (row >> 5) + ry0 + (t >> 1);
            const int gq = (row & 31) + cx0 + (t & 1);
            v8s xv = z8;
            if ((unsigned)gr < 32u && (unsigned)gq < 32u)
                xv = *(const v8s*)(XtB + (size_t)((gr * 32 + gq) * 512 + c0 + cg * 8));
            *(v8s*)&Xs[ldso] = xv;
        }
        __syncthreads();
        // 4 k-steps of 32 (one per tap), 2x4 MFMA each
#pragma unroll
        for (int s = 0; s < 4; s++) {
            const int kb = s * 32 + l4 * 8;
            v8s af[2], bf[4];
#pragma unroll
            for (int i = 0; i < 2; i++)
                af[i] = *(const v8s*)&Wt[(wo + i * 16 + l15) * KS + kb];
#pragma unroll
            for (int j = 0; j < 4; j++)
                bf[j] = *(const v8s*)&Xs[(wn + j * 16 + l15) * KS + kb];
#pragma unroll
            for (int i = 0; i < 2; i++)
#pragma unroll
                for (int j = 0; j < 4; j++)
                    acc[i][j] = __builtin_amdgcn_mfma_f32_16x16x32_bf16(
                        af[i], bf[j], acc[i][j], 0, 0, 0);
        }
    }

    // ---- epilogue: demod * acc + bias + noise, leaky relu ----
    const float* db = dmod + b * COUT;
    float nz[4];
    int ooff[4];
#pragma unroll
    for (int j = 0; j < 4; j++) {
        const int n = wn + j * 16 + l15;
        const int Y = 2 * (r0 + (n >> 5)) + py, X = 2 * (n & 31) + px;
        nz[j] = noise[b * 4096 + Y * 64 + X];
        ooff[j] = Y * 64 + X;
    }
    float* outB = out + (size_t)b * COUT * 4096;
#pragma unroll
    for (int i = 0; i < 2; i++) {
        const int ob = o0 + wo + i * 16 + l4 * 4;
        float4 d4 = *(const float4*)(db + ob);
        float4 b4 = *(const float4*)(bias + ob);
        const float dv[4] = {d4.x, d4.y, d4.z, d4.w};
        const float bv[4] = {b4.x, b4.y, b4.z, b4.w};
#pragma unroll
        for (int reg = 0; reg < 4; reg++) {
            float* orow = outB + (size_t)(ob + reg) * 4096;
#pragma unroll
            for (int j = 0; j < 4; j++) {
                float v = acc[i][j][reg] * dv[reg] + bv[reg] + nz[j];
                orow[ooff[j]] = v > 0.f ? v : 0.2f * v;
            }
        }
    }
}

// ---------------------------------------------------------------------------
extern "C" void kernel_launch(void* const* d_in, const int* in_sizes, int n_in,
                              void* d_out, int out_size, void* d_ws, size_t ws_size,
                              hipStream_t stream) {
    const float* x      = (const float*)d_in[0];
    const float* style  = (const float*)d_in[1];
    const float* noise  = (const float*)d_in[2];
    const float* conv_w = (const float*)d_in[3];
    const float* fc_w   = (const float*)d_in[4];
    const float* fc_b   = (const float*)d_in[5];
    const float* bias   = (const float*)d_in[6];
    float* out = (float*)d_out;

    float* ws = (float*)d_ws;
    float* m    = ws;            // 8*512
    float* dmod = ws + 4096;     // 8*512
    float* q    = ws + 8192;     // 512*512
    ushort_t* XtU = (ushort_t*)(ws + 270336);  // 8*32*32*512 bf16
    ushort_t* WbU = XtU + 4194304;             // 4*16*4*4*512*8 bf16

    k_style<<<BB, 256, 0, stream>>>(style, fc_w, fc_b, m);
    k_wprep<<<(COUT * CIN + 255) / 256, 256, 0, stream>>>(conv_w, q, WbU);
    k_xprep<<<dim3(32, BB), 256, 0, stream>>>(x, m, XtU);
    k_demod<<<1024, 256, 0, stream>>>(m, q, dmod);
    k_gemm<<<dim3(8, 8, 32), 256, 0, stream>>>(XtU, WbU, dmod, bias, noise, out);
}

// Round 7
// 231.762 us; speedup vs baseline: 21.7843x; 1.3398x over previous
//
#include <hip/hip_runtime.h>

typedef short v8s __attribute__((ext_vector_type(8)));
typedef float f32x4 __attribute__((ext_vector_type(4)));
typedef unsigned short ushort_t;

#define BB    8
#define CIN   512
#define COUT  512
#define SDIM  512

static __device__ __forceinline__ ushort_t f2bf(float f) {
    union { float f; unsigned u; } un; un.f = f;
    unsigned r = un.u + 0x7FFF + ((un.u >> 16) & 1);  // round-to-nearest-even
    return (ushort_t)(r >> 16);
}

// ---------------------------------------------------------------------------
// m[b,c] = 1 + style[b,:] @ fc_w[c,:] + fc_b[c]   (grid: (2, B), one c/thread)
// ---------------------------------------------------------------------------
__global__ void k_style(const float* __restrict__ style, const float* __restrict__ fc_w,
                        const float* __restrict__ fc_b, float* __restrict__ m) {
    __shared__ float sst[SDIM];
    const int b = blockIdx.y;
    for (int k = threadIdx.x; k < SDIM; k += 256) sst[k] = style[b * SDIM + k];
    __syncthreads();
    const int c = blockIdx.x * 256 + threadIdx.x;
    float acc = fc_b[c];
    const float* wr = fc_w + c * SDIM;
    for (int k = 0; k < SDIM; k += 4) {
        float4 w4 = *(const float4*)(wr + k);
        acc += w4.x * sst[k] + w4.y * sst[k + 1] + w4.z * sst[k + 2] + w4.w * sst[k + 3];
    }
    m[b * CIN + c] = acc + 1.0f;
}

// ---------------------------------------------------------------------------
// q[o,c] = sum_k w^2 ; Wb bf16 phase-combined weights:
// Wb[p][ch=c>>5][t][kg=(c>>3)&3][o][c&7]
// ---------------------------------------------------------------------------
__global__ void k_wprep(const float* __restrict__ conv_w, float* __restrict__ q,
                        ushort_t* __restrict__ Wb) {
    const int idx = blockIdx.x * 256 + threadIdx.x;  // o*512 + c
    if (idx >= COUT * CIN) return;
    const int o = idx >> 9, c = idx & 511;
    float w[3][3];
    const float* wp = conv_w + idx * 9;
    float qs = 0.f;
    for (int i = 0; i < 3; i++)
        for (int j = 0; j < 3; j++) {
            float v = wp[i * 3 + j];
            w[i][j] = v;
            qs += v * v;
        }
    q[idx] = qs;
    const int ch = c >> 5, kg = (c >> 3) & 3, c8 = c & 7;
    for (int py = 0; py < 2; py++) {
        float rs[2][3];
        for (int kx = 0; kx < 3; kx++) {
            rs[0][kx] = (py == 0) ? w[0][kx] : w[0][kx] + w[1][kx];
            rs[1][kx] = (py == 0) ? w[1][kx] + w[2][kx] : w[2][kx];
        }
        for (int px = 0; px < 2; px++) {
            const int p = py * 2 + px;
            float vals[4];
            if (px == 0) {
                vals[0] = rs[0][0];
                vals[1] = rs[0][1] + rs[0][2];
                vals[2] = rs[1][0];
                vals[3] = rs[1][1] + rs[1][2];
            } else {
                vals[0] = rs[0][0] + rs[0][1];
                vals[1] = rs[0][2];
                vals[2] = rs[1][0] + rs[1][1];
                vals[3] = rs[1][2];
            }
            for (int t = 0; t < 4; t++)
                Wb[(size_t)p * (16 * 4 * 4 * 512 * 8) + (size_t)ch * (4 * 4 * 512 * 8)
                   + ((size_t)(t * 4 + kg) * 512 + o) * 8 + c8] = f2bf(vals[t]);
        }
    }
}

// ---------------------------------------------------------------------------
// d[b,o] = rsqrt( sum_c m[b,c]^2 * q[o,c] + 1e-8 ) — one wave per (b,o)
// ---------------------------------------------------------------------------
__global__ void k_demod(const float* __restrict__ m, const float* __restrict__ q,
                        float* __restrict__ d) {
    const int w = (blockIdx.x * 256 + threadIdx.x) >> 6;  // 0..4095
    const int L = threadIdx.x & 63;
    const int b = w >> 9, o = w & 511;
    float4 q1 = *(const float4*)(q + o * 512 + L * 8);
    float4 q2 = *(const float4*)(q + o * 512 + L * 8 + 4);
    float4 m1 = *(const float4*)(m + b * 512 + L * 8);
    float4 m2 = *(const float4*)(m + b * 512 + L * 8 + 4);
    float acc = m1.x * m1.x * q1.x + m1.y * m1.y * q1.y + m1.z * m1.z * q1.z +
                m1.w * m1.w * q1.w + m2.x * m2.x * q2.x + m2.y * m2.y * q2.y +
                m2.z * m2.z * q2.z + m2.w * m2.w * q2.w;
    for (int off = 32; off; off >>= 1) acc += __shfl_down(acc, off, 64);
    if (L == 0) d[w] = rsqrtf(acc + 1e-8f);
}

// ---------------------------------------------------------------------------
// Xt[b][r][q][c] = bf16( x[b][c][r][q] * m[b][c] )   (c-contiguous transpose)
// ---------------------------------------------------------------------------
__global__ void k_xprep(const float* __restrict__ x, const float* __restrict__ m,
                        ushort_t* __restrict__ Xt) {
    __shared__ __align__(16) ushort_t lt[32 * 528];  // [q][c], c-stride 528
    const int r = blockIdx.x, b = blockIdx.y, t = threadIdx.x;
    for (int s = t; s < 4096; s += 256) {  // (c, q-quad)
        const int c = s >> 3, q4 = (s & 7) * 4;
        float4 v = *(const float4*)(x + (((size_t)(b * CIN + c) * 32 + r) * 32 + q4));
        const float mv = m[b * CIN + c];
        lt[(q4 + 0) * 528 + c] = f2bf(v.x * mv);
        lt[(q4 + 1) * 528 + c] = f2bf(v.y * mv);
        lt[(q4 + 2) * 528 + c] = f2bf(v.z * mv);
        lt[(q4 + 3) * 528 + c] = f2bf(v.w * mv);
    }
    __syncthreads();
    for (int s = t; s < 2048; s += 256) {  // (q, c-group of 8)
        const int qq = s >> 6, c8 = s & 63;
        v8s v = *(v8s*)&lt[qq * 528 + c8 * 8];
        *(v8s*)(Xt + (((size_t)(b * 32 + r) * 32 + qq) * 512 + c8 * 8)) = v;
    }
}

// ---------------------------------------------------------------------------
// k_gemm: round-6-verified structure + register-prefetch software pipeline.
// Per (b,p): O[o,n] = sum_k W[o][k]*X[n][k], k = tap*32 + c_local per
// 128-wide chunk (4 taps x 32 ch), 16 chunks. Block 64o x 128n, 4 waves
// of 32x64. Index formulas verbatim round 6; only the schedule changed:
// chunk c+1's global loads issue into registers while chunk c computes.
// ---------------------------------------------------------------------------
#define KS 136  // padded k-stride (272 B: 16B-aligned, 2-way banks only)

__global__ __launch_bounds__(256, 3) void k_gemm(
    const ushort_t* __restrict__ Xt, const ushort_t* __restrict__ Wb,
    const float* __restrict__ dmod, const float* __restrict__ bias,
    const float* __restrict__ noise, float* __restrict__ out) {
    __shared__ __align__(16) ushort_t Wt[64 * KS];   // [o-local][k]
    __shared__ __align__(16) ushort_t Xs[128 * KS];  // [n-local][k]

    const int tid = threadIdx.x;
    const int L = tid & 63, wid = tid >> 6;
    const int o0 = blockIdx.x * 64;
    const int r0 = blockIdx.y * 4;
    const int b = blockIdx.z >> 2, p = blockIdx.z & 3;
    const int py = p >> 1, px = p & 1;
    const int ry0 = py ? 0 : -1, cx0 = px ? 0 : -1;
    const int wo = (wid >> 1) * 32, wn = (wid & 1) * 64;
    const int l15 = L & 15, l4 = L >> 4;

    const ushort_t* XtB = Xt + (size_t)b * (32 * 32 * 512);
    const ushort_t* WbP = Wb + (size_t)p * (16 * 4 * 4 * 512 * 8);
    const v8s z8 = {0, 0, 0, 0, 0, 0, 0, 0};

    f32x4 acc[2][4];
#pragma unroll
    for (int i = 0; i < 2; i++)
#pragma unroll
        for (int j = 0; j < 4; j++) acc[i][j] = {0.f, 0.f, 0.f, 0.f};

    // prefetch registers for one chunk's staging data
    v8s rw[4], rx[8];

    // load chunk at channel base c0 into registers (formulas verbatim R6)
    auto loadc = [&](int c0) {
        const ushort_t* WbC = WbP + (size_t)(c0 >> 5) * (4 * 4 * 512 * 8);
#pragma unroll
        for (int i = 0; i < 8; i++) {
            const int slot = tid + i * 256;
            const int row = slot >> 4, t = (slot >> 2) & 3, cg = slot & 3;
            if (i < 4)
                rw[i] =
                    *(const v8s*)(WbC + ((size_t)((t * 4 + cg) * 512 + o0 + row)) * 8);
            const int gr = r0 + (row >> 5) + ry0 + (t >> 1);
            const int gq = (row & 31) + cx0 + (t & 1);
            v8s xv = z8;
            if ((unsigned)gr < 32u && (unsigned)gq < 32u)
                xv = *(const v8s*)(XtB + (size_t)((gr * 32 + gq) * 512 + c0 + cg * 8));
            rx[i] = xv;
        }
    };

    loadc(0);
    for (int c0 = 0; c0 < CIN; c0 += 32) {
        __syncthreads();  // previous chunk's LDS reads done
        // store prefetched registers to LDS (formulas verbatim R6)
#pragma unroll
        for (int i = 0; i < 8; i++) {
            const int slot = tid + i * 256;
            const int row = slot >> 4, t = (slot >> 2) & 3, cg = slot & 3;
            const int ldso = row * KS + t * 32 + cg * 8;
            if (i < 4) *(v8s*)&Wt[ldso] = rw[i];
            *(v8s*)&Xs[ldso] = rx[i];
        }
        __syncthreads();  // LDS ready
        // issue next chunk's global loads; they retire during compute below
        if (c0 + 32 < CIN) loadc(c0 + 32);
        // 4 k-steps of 32 (one per tap), 2x4 MFMA each
#pragma unroll
        for (int s = 0; s < 4; s++) {
            const int kb = s * 32 + l4 * 8;
            v8s af[2], bf[4];
#pragma unroll
            for (int i = 0; i < 2; i++)
                af[i] = *(const v8s*)&Wt[(wo + i * 16 + l15) * KS + kb];
#pragma unroll
            for (int j = 0; j < 4; j++)
                bf[j] = *(const v8s*)&Xs[(wn + j * 16 + l15) * KS + kb];
#pragma unroll
            for (int i = 0; i < 2; i++)
#pragma unroll
                for (int j = 0; j < 4; j++)
                    acc[i][j] = __builtin_amdgcn_mfma_f32_16x16x32_bf16(
                        af[i], bf[j], acc[i][j], 0, 0, 0);
        }
    }

    // ---- epilogue: demod * acc + bias + noise, leaky relu ----
    const float* db = dmod + b * COUT;
    float nz[4];
    int ooff[4];
#pragma unroll
    for (int j = 0; j < 4; j++) {
        const int n = wn + j * 16 + l15;
        const int Y = 2 * (r0 + (n >> 5)) + py, X = 2 * (n & 31) + px;
        nz[j] = noise[b * 4096 + Y * 64 + X];
        ooff[j] = Y * 64 + X;
    }
    float* outB = out + (size_t)b * COUT * 4096;
#pragma unroll
    for (int i = 0; i < 2; i++) {
        const int ob = o0 + wo + i * 16 + l4 * 4;
        float4 d4 = *(const float4*)(db + ob);
        float4 b4 = *(const float4*)(bias + ob);
        const float dv[4] = {d4.x, d4.y, d4.z, d4.w};
        const float bv[4] = {b4.x, b4.y, b4.z, b4.w};
#pragma unroll
        for (int reg = 0; reg < 4; reg++) {
            float* orow = outB + (size_t)(ob + reg) * 4096;
#pragma unroll
            for (int j = 0; j < 4; j++) {
                float v = acc[i][j][reg] * dv[reg] + bv[reg] + nz[j];
                orow[ooff[j]] = v > 0.f ? v : 0.2f * v;
            }
        }
    }
}

// ---------------------------------------------------------------------------
extern "C" void kernel_launch(void* const* d_in, const int* in_sizes, int n_in,
                              void* d_out, int out_size, void* d_ws, size_t ws_size,
                              hipStream_t stream) {
    const float* x      = (const float*)d_in[0];
    const float* style  = (const float*)d_in[1];
    const float* noise  = (const float*)d_in[2];
    const float* conv_w = (const float*)d_in[3];
    const float* fc_w   = (const float*)d_in[4];
    const float* fc_b   = (const float*)d_in[5];
    const float* bias   = (const float*)d_in[6];
    float* out = (float*)d_out;

    float* ws = (float*)d_ws;
    float* m    = ws;            // 8*512
    float* dmod = ws + 4096;     // 8*512
    float* q    = ws + 8192;     // 512*512
    ushort_t* XtU = (ushort_t*)(ws + 270336);  // 8*32*32*512 bf16
    ushort_t* WbU = XtU + 4194304;             // 4*16*4*4*512*8 bf16

    k_style<<<dim3(2, BB), 256, 0, stream>>>(style, fc_w, fc_b, m);
    k_wprep<<<(COUT * CIN + 255) / 256, 256, 0, stream>>>(conv_w, q, WbU);
    k_xprep<<<dim3(32, BB), 256, 0, stream>>>(x, m, XtU);
    k_demod<<<1024, 256, 0, stream>>>(m, q, dmod);
    k_gemm<<<dim3(8, 8, 32), 256, 0, stream>>>(XtU, WbU, dmod, bias, noise, out);
}